// Round 3
// baseline (27.005 us; speedup 1.0000x reference)
//
#include <hip/hip_runtime.h>
#include <hip/hip_bf16.h>

// PhaseSpecificInput: per-row 32-nnz gather-sum over fake-quantized weight,
// computing ONLY the 128-wide phase slice selected by ply//10.
//
// Round-3 structure: each 32-lane HALF-WAVE owns one full row:
//   - 32 float4 (16B/lane) gathers, fully unrolled, all independent
//     -> up to 64 outstanding loads per wave, zero cross-lane combines
//   - lanes store the row directly (32 x 16B = 512B; the wave's two rows are
//     adjacent -> 1KB contiguous store per wave)

#define L1_PS      128
#define WIDTH      768           // COUNT * L1_PS
#define NNZ_PER    32
#define BUCKET_DIV 10            // MAX_PLY / COUNT
#define QUANT      127.0f
#define INV_QUANT  (1.0f / 127.0f)

__global__ __launch_bounds__(256) void psi_kernel(
    const int*   __restrict__ cols,    // [NNZ]
    const float* __restrict__ values,  // [NNZ]
    const int*   __restrict__ ply,     // [M]
    const float* __restrict__ weight,  // [NF, 768]
    const float* __restrict__ bias,    // [768]
    float*       __restrict__ out,     // [M, 128]
    int M)
{
    const int wave = threadIdx.x >> 6;            // 4 waves / block
    const int lane = threadIdx.x & 63;
    const int half = lane >> 5;                   // each half-wave owns a row
    const int l32  = lane & 31;                   // lane owns 4 output cols
    const int row  = (blockIdx.x * 4 + wave) * 2 + half;
    if (row >= M) return;

    const int bucket = ply[row] / BUCKET_DIV;     // uniform within half-wave
    const int coff   = bucket * L1_PS + l32 * 4;

    float4 acc = make_float4(0.f, 0.f, 0.f, 0.f);

    const int jbase = row * NNZ_PER;
    #pragma unroll
    for (int t = 0; t < NNZ_PER; ++t) {
        const int   c = cols[jbase + t];          // uniform within half (L1 broadcast)
        const float v = values[jbase + t];
        const float4 w = *(const float4*)(weight + (size_t)c * WIDTH + coff);
        acc.x = fmaf(rintf(w.x * QUANT) * INV_QUANT, v, acc.x);
        acc.y = fmaf(rintf(w.y * QUANT) * INV_QUANT, v, acc.y);
        acc.z = fmaf(rintf(w.z * QUANT) * INV_QUANT, v, acc.z);
        acc.w = fmaf(rintf(w.w * QUANT) * INV_QUANT, v, acc.w);
    }

    const float4 b = *(const float4*)(bias + coff);
    float4 r;
    r.x = fminf(fmaxf(acc.x + rintf(b.x * QUANT) * INV_QUANT, 0.f), 1.f);
    r.y = fminf(fmaxf(acc.y + rintf(b.y * QUANT) * INV_QUANT, 0.f), 1.f);
    r.z = fminf(fmaxf(acc.z + rintf(b.z * QUANT) * INV_QUANT, 0.f), 1.f);
    r.w = fminf(fmaxf(acc.w + rintf(b.w * QUANT) * INV_QUANT, 0.f), 1.f);
    *(float4*)(out + (size_t)row * L1_PS + l32 * 4) = r;
}

extern "C" void kernel_launch(void* const* d_in, const int* in_sizes, int n_in,
                              void* d_out, int out_size, void* d_ws, size_t ws_size,
                              hipStream_t stream) {
    const int*   fi     = (const int*)d_in[0];      // [2, NNZ] int32
    const float* values = (const float*)d_in[1];
    const int*   ply    = (const int*)d_in[2];
    const float* weight = (const float*)d_in[3];
    const float* bias   = (const float*)d_in[4];
    float*       out    = (float*)d_out;

    const int NNZ  = in_sizes[1];
    const int* cols = fi + NNZ;                     // second row of feature_indices
    const int M = out_size / L1_PS;

    dim3 grid((M + 7) / 8), block(256);             // 8 rows / block
    hipLaunchKernelGGL(psi_kernel, grid, block, 0, stream,
                       cols, values, ply, weight, bias, out, M);
}

// Round 4
// 26.764 us; speedup vs baseline: 1.0090x; 1.0090x over previous
//
#include <hip/hip_runtime.h>
#include <hip/hip_bf16.h>

// PhaseSpecificInput: per-row 32-nnz gather-sum over fake-quantized weight,
// computing ONLY the 128-wide phase slice selected by ply//10.
//
// Round-4 structure (= round-2 best config + LDS index staging):
//   - 1 wave per row, two 16-nnz halves, float4 gathers, shfl(32) combine
//   - block stages its 4 rows' cols/values into LDS with 2 coalesced loads;
//     inner loop reads them via broadcast ds_read instead of 32 redundant
//     uniform-address global loads per wave -> vmem issue is ~90% gathers.

#define L1_PS      128
#define WIDTH      768           // COUNT * L1_PS
#define NNZ_PER    32
#define BUCKET_DIV 10            // MAX_PLY / COUNT
#define QUANT      127.0f
#define INV_QUANT  (1.0f / 127.0f)

__global__ __launch_bounds__(256) void psi_kernel(
    const int*   __restrict__ cols,    // [NNZ]
    const float* __restrict__ values,  // [NNZ]
    const int*   __restrict__ ply,     // [M]
    const float* __restrict__ weight,  // [NF, 768]
    const float* __restrict__ bias,    // [768]
    float*       __restrict__ out,     // [M, 128]
    int M)
{
    __shared__ int   s_cols[4][NNZ_PER];
    __shared__ float s_vals[4][NNZ_PER];

    const int tid   = threadIdx.x;
    const int rbase = blockIdx.x * 4;           // 4 rows per block

    // stage this block's 128 cols + 128 values (2 coalesced 512B loads)
    if (tid < 128) {
        ((int*)s_cols)[tid] = cols[rbase * NNZ_PER + tid];
    } else {
        ((float*)s_vals)[tid - 128] = values[rbase * NNZ_PER + (tid - 128)];
    }
    __syncthreads();

    const int wave = tid >> 6;                  // 4 waves / block, 1 row each
    const int lane = tid & 63;
    const int half = lane >> 5;                 // which 16 nnz
    const int l32  = lane & 31;                 // lane owns 4 output cols
    const int row  = rbase + wave;
    if (row >= M) return;

    const int bucket = ply[row] / BUCKET_DIV;   // wave-uniform
    const int coff   = bucket * L1_PS + l32 * 4;

    float4 acc = make_float4(0.f, 0.f, 0.f, 0.f);

    const int tb = half * 16;
    #pragma unroll
    for (int t = 0; t < 16; ++t) {
        const int   c = s_cols[wave][tb + t];   // broadcast ds_read
        const float v = s_vals[wave][tb + t];
        const float4 w = *(const float4*)(weight + (size_t)c * WIDTH + coff);
        acc.x = fmaf(rintf(w.x * QUANT) * INV_QUANT, v, acc.x);
        acc.y = fmaf(rintf(w.y * QUANT) * INV_QUANT, v, acc.y);
        acc.z = fmaf(rintf(w.z * QUANT) * INV_QUANT, v, acc.z);
        acc.w = fmaf(rintf(w.w * QUANT) * INV_QUANT, v, acc.w);
    }

    // combine the two 16-nnz halves (lane <-> lane^32)
    acc.x += __shfl_xor(acc.x, 32);
    acc.y += __shfl_xor(acc.y, 32);
    acc.z += __shfl_xor(acc.z, 32);
    acc.w += __shfl_xor(acc.w, 32);

    if (half == 0) {
        const float4 b = *(const float4*)(bias + coff);
        float4 r;
        r.x = fminf(fmaxf(acc.x + rintf(b.x * QUANT) * INV_QUANT, 0.f), 1.f);
        r.y = fminf(fmaxf(acc.y + rintf(b.y * QUANT) * INV_QUANT, 0.f), 1.f);
        r.z = fminf(fmaxf(acc.z + rintf(b.z * QUANT) * INV_QUANT, 0.f), 1.f);
        r.w = fminf(fmaxf(acc.w + rintf(b.w * QUANT) * INV_QUANT, 0.f), 1.f);
        *(float4*)(out + (size_t)row * L1_PS + l32 * 4) = r;
    }
}

extern "C" void kernel_launch(void* const* d_in, const int* in_sizes, int n_in,
                              void* d_out, int out_size, void* d_ws, size_t ws_size,
                              hipStream_t stream) {
    const int*   fi     = (const int*)d_in[0];      // [2, NNZ] int32
    const float* values = (const float*)d_in[1];
    const int*   ply    = (const int*)d_in[2];
    const float* weight = (const float*)d_in[3];
    const float* bias   = (const float*)d_in[4];
    float*       out    = (float*)d_out;

    const int NNZ  = in_sizes[1];
    const int* cols = fi + NNZ;                     // second row of feature_indices
    const int M = out_size / L1_PS;

    dim3 grid((M + 3) / 4), block(256);             // 4 rows / block, 32 waves/CU
    hipLaunchKernelGGL(psi_kernel, grid, block, 0, stream,
                       cols, values, ply, weight, bias, out, M);
}